// Round 7
// baseline (1252.782 us; speedup 1.0000x reference)
//
#include <hip/hip_runtime.h>
#include <stdint.h>

namespace {

constexpr int DIM  = 180;
constexpr int LL   = 14336;
constexpr int B    = 16;
constexpr int EQKV = 540;
constexpr int EPAD = 192;

// pipeline layout
constexpr int QROW = 544;      // u16 per qkv token row (540 + 4 pad), 1088 B
constexpr int K1T  = 64;       // tokens per K1 block
constexpr int K2T  = 112;      // tokens per K2 block (16 windows)

// fused-fallback (R5) layout
constexpr int F_T = 56;
constexpr int QT_STRIDE = 584;
constexpr int XS_STRIDE = 200;
constexpr int QT_U16  = F_T * QT_STRIDE;
constexpr int XS_U16  = 32 * XS_STRIDE;
constexpr int LDS_U16 = QT_U16 + XS_U16 + 544;

typedef __attribute__((ext_vector_type(8))) short bf16x8;
typedef __attribute__((ext_vector_type(4))) float f32x4;

union Frag { bf16x8 v; uint32_t u[4]; unsigned short s[8]; };

__device__ __forceinline__ unsigned short f2b(float f) {
  uint32_t u = __builtin_bit_cast(uint32_t, f);
  u = (u + 0x7fffu + ((u >> 16) & 1u)) >> 16;   // RNE
  return (unsigned short)u;
}
__device__ __forceinline__ uint32_t pack2(float lo, float hi) {
  return (uint32_t)f2b(lo) | ((uint32_t)f2b(hi) << 16);
}
__device__ __forceinline__ float blo(uint32_t u) { return __builtin_bit_cast(float, u << 16); }
__device__ __forceinline__ float bhi(uint32_t u) { return __builtin_bit_cast(float, u & 0xffff0000u); }
__device__ __forceinline__ f32x4 zero4() { f32x4 z = {0.f,0.f,0.f,0.f}; return z; }
__device__ __forceinline__ bf16x8 zfrag() {
  Frag f; f.u[0]=f.u[1]=f.u[2]=f.u[3]=0u; return f.v;
}

} // namespace

// ---- prep: weights -> bf16 in three layouts -------------------------------
// wqkv_b[576][192]  (rows >=540 zero, cols >=180 zero)
// wo_h32[192][192]  (R5 fused layout: col = h*32+d)
// wo_nat[192][192]  (natural col = e, zero-padded)
__global__ __launch_bounds__(1024) void la_prep(
    const float* __restrict__ Wq, const float* __restrict__ Wkv,
    const float* __restrict__ Wo, unsigned short* __restrict__ wqkv_b,
    unsigned short* __restrict__ wo_h32, unsigned short* __restrict__ wo_nat) {
  const int idx = (int)(blockIdx.x * 1024 + threadIdx.x);
  if (idx < 576 * 192) {
    const int e = idx / 192, c = idx - e * 192;
    float v = 0.f;
    if (e < EQKV && c < DIM)
      v = (e < DIM) ? Wq[e * DIM + c] : Wkv[(size_t)(e - DIM) * DIM + c];
    wqkv_b[idx] = f2b(v);
  } else if (idx < 576 * 192 + 192 * 192) {
    const int k = idx - 576 * 192;
    const int o = k / 192, cc = k - o * 192;
    const int h = cc >> 5, d = cc & 31;
    float v = 0.f;
    if (o < DIM && d < 30) v = Wo[o * DIM + h * 30 + d];
    wo_h32[k] = f2b(v);
  } else {
    const int k = idx - 576 * 192 - 192 * 192;
    const int o = k / 192, c = k - o * 192;
    float v = 0.f;
    if (o < DIM && c < DIM) v = Wo[o * DIM + c];
    wo_nat[k] = f2b(v);
  }
}

// ---- K1: qkv[t][e] = Wqkv @ x, streamed to HBM ----------------------------
__global__ __launch_bounds__(512, 4) void k1_qkv(
    const float* __restrict__ fmap, const unsigned short* __restrict__ wqkv,
    unsigned short* __restrict__ qkv, int b0) {
  __shared__ __align__(16) unsigned short xs[K1T * 200];  // [t][c] 25.6 KB

  const int tid  = (int)threadIdx.x;
  const int wave = tid >> 6;
  const int lane = tid & 63;
  const int l15  = lane & 15;
  const int g    = lane >> 4;

  const int bl = (int)blockIdx.x / 224;          // slice-local batch
  const int b  = b0 + bl;
  const int t0 = ((int)blockIdx.x - bl * 224) * K1T;

  // stage 64 tokens x 192 channels (coalesced 256B rows)
#pragma unroll
  for (int it = 0; it < 6; ++it) {
    const int idx = tid + it * 512;              // 192 * 16
    const int c = idx >> 4;
    const int t = (idx & 15) * 4;
    float4 v = {0.f, 0.f, 0.f, 0.f};
    if (c < DIM)
      v = *(const float4*)(fmap + ((size_t)b * DIM + c) * LL + t0 + t);
    xs[(t + 0) * 200 + c] = f2b(v.x);
    xs[(t + 1) * 200 + c] = f2b(v.y);
    xs[(t + 2) * 200 + c] = f2b(v.z);
    xs[(t + 3) * 200 + c] = f2b(v.w);
  }
  __syncthreads();

  const int nmt = (wave < 4) ? 5 : 4;            // 36 m-tiles = 8*4 + 4
  f32x4 acc[5][4];
#pragma unroll
  for (int i = 0; i < 5; ++i)
#pragma unroll
    for (int n = 0; n < 4; ++n) acc[i][n] = zero4();

#pragma unroll
  for (int ks = 0; ks < 6; ++ks) {
    const int c0 = ks * 32 + g * 8;
    bf16x8 bfr[4];
#pragma unroll
    for (int n = 0; n < 4; ++n)
      bfr[n] = *(const bf16x8*)(xs + (n * 16 + l15) * 200 + c0);
#pragma unroll
    for (int i = 0; i < 5; ++i) {
      if (i < nmt) {
        const int e = (wave + i * 8) * 16 + l15;  // < 576, rows >=540 are zero
        const bf16x8 a = *(const bf16x8*)(wqkv + (size_t)e * EPAD + c0);
#pragma unroll
        for (int n = 0; n < 4; ++n)
          acc[i][n] = __builtin_amdgcn_mfma_f32_16x16x32_bf16(a, bfr[n], acc[i][n], 0, 0, 0);
      }
    }
  }

  // store: C col=t=lane&15, row e=(lane>>4)*4+r -> [t][e0..e0+4) 8B chunks
  const size_t rowbase = (size_t)bl * LL + t0;
#pragma unroll
  for (int i = 0; i < 5; ++i) {
    if (i < nmt) {
      const int e0 = (wave + i * 8) * 16 + g * 4;
      if (e0 < EQKV) {                            // 540 is 4-aligned: clean
#pragma unroll
        for (int n = 0; n < 4; ++n) {
          const int t = n * 16 + l15;
          uint2 pk;
          pk.x = pack2(acc[i][n][0], acc[i][n][1]);
          pk.y = pack2(acc[i][n][2], acc[i][n][3]);
          *(uint2*)(qkv + (rowbase + t) * QROW + e0) = pk;
        }
      }
    }
  }
}

// ---- K2: windowed attention (gather from qkv) + out-proj ------------------
__global__ __launch_bounds__(512, 4) void k2_attn_oproj(
    const unsigned short* __restrict__ qkv, const unsigned short* __restrict__ wo,
    const float* __restrict__ bo, float* __restrict__ out, int b0) {
  __shared__ __align__(16) unsigned short att[K2T * 200];  // [t][e] 44.8 KB

  const int tid  = (int)threadIdx.x;
  const int wave = tid >> 6;
  const int lane = tid & 63;
  const int l15  = lane & 15;
  const int g    = lane >> 4;

  const int bl = (int)blockIdx.x >> 7;
  const int b  = b0 + bl;
  const int t0 = ((int)blockIdx.x & 127) * K2T;
  const size_t slbase = (size_t)bl * LL + t0;

  // attention: 384 i-pair tasks = 16 w x 6 h x 4 pairs
  if (tid < 384) {
    const float scale = 0.18257418583505536f;    // 30^-0.5
    const int w   = tid / 24;
    const int rem = tid - w * 24;
    const int h   = rem >> 2;
    const int p   = rem & 3;
    const int i0  = 2 * p;
    const bool two = (p < 3);
    const size_t twb = slbase + w * 7;
    const int hq = h * 30;

    uint32_t q0[15], q1[15];
    {
      const uint32_t* qp0 = (const uint32_t*)(qkv + (twb + i0) * QROW + hq);
      const uint32_t* qp1 = (const uint32_t*)(qkv + (twb + i0 + (two ? 1 : 0)) * QROW + hq);
#pragma unroll
      for (int dp = 0; dp < 15; ++dp) { q0[dp] = qp0[dp]; q1[dp] = qp1[dp]; }
    }
    float d0[7], d1[7];
#pragma unroll
    for (int j = 0; j < 7; ++j) {
      const uint32_t* kp = (const uint32_t*)(qkv + (twb + j) * QROW + DIM + hq);
      float s0 = 0.f, s1 = 0.f;
#pragma unroll
      for (int dp = 0; dp < 15; ++dp) {
        const uint32_t ku = kp[dp];
        const float kl = blo(ku), kh = bhi(ku);
        s0 += blo(q0[dp]) * kl + bhi(q0[dp]) * kh;
        s1 += blo(q1[dp]) * kl + bhi(q1[dp]) * kh;
      }
      d0[j] = s0; d1[j] = s1;
    }
    float aw0[7], aw1[7];
    {
      float mx0 = d0[0], mx1 = d1[0];
#pragma unroll
      for (int j = 1; j < 7; ++j) { mx0 = fmaxf(mx0, d0[j]); mx1 = fmaxf(mx1, d1[j]); }
      float s0 = 0.f, s1 = 0.f;
#pragma unroll
      for (int j = 0; j < 7; ++j) {
        aw0[j] = __expf(scale * (d0[j] - mx0)); s0 += aw0[j];
        aw1[j] = __expf(scale * (d1[j] - mx1)); s1 += aw1[j];
      }
      const float r0 = 1.f / s0, r1 = 1.f / s1;
#pragma unroll
      for (int j = 0; j < 7; ++j) { aw0[j] *= r0; aw1[j] *= r1; }
    }
    float o0[30], o1[30];
#pragma unroll
    for (int d = 0; d < 30; ++d) { o0[d] = 0.f; o1[d] = 0.f; }
#pragma unroll
    for (int j = 0; j < 7; ++j) {
      const uint32_t* vp = (const uint32_t*)(qkv + (twb + j) * QROW + 2 * DIM + hq);
      const float a0 = aw0[j], a1 = aw1[j];
#pragma unroll
      for (int dp = 0; dp < 15; ++dp) {
        const uint32_t vu = vp[dp];
        const float vl = blo(vu), vh = bhi(vu);
        o0[2 * dp]     += a0 * vl;  o0[2 * dp + 1] += a0 * vh;
        o1[2 * dp]     += a1 * vl;  o1[2 * dp + 1] += a1 * vh;
      }
    }
    unsigned short* ar0 = att + (w * 7 + i0) * 200 + hq;
#pragma unroll
    for (int dp = 0; dp < 15; ++dp)
      *(uint32_t*)(ar0 + 2 * dp) = pack2(o0[2 * dp], o0[2 * dp + 1]);
    if (two) {
      unsigned short* ar1 = ar0 + 200;
#pragma unroll
      for (int dp = 0; dp < 15; ++dp)
        *(uint32_t*)(ar1 + 2 * dp) = pack2(o1[2 * dp], o1[2 * dp + 1]);
    }
  }
  // zero K-pad cols [180,192) of every att row
  for (int idx = tid; idx < K2T * 6; idx += 512) {
    const int t = idx / 6;
    const int j = idx - t * 6;
    *(uint32_t*)(att + t * 200 + DIM + 2 * j) = 0u;
  }
  __syncthreads();

  // out-proj: y = Wo @ att + bo   (12 mt x 7 nt, K=192)
  const int w_m = wave >> 1;
  const int w_n = wave & 1;
  const int ntb = w_n * 4;
  const int nnt = w_n ? 3 : 4;
  f32x4 acc[3][4];
#pragma unroll
  for (int i = 0; i < 3; ++i)
#pragma unroll
    for (int n = 0; n < 4; ++n) acc[i][n] = zero4();
#pragma unroll
  for (int ks = 0; ks < 6; ++ks) {
    const int c0 = ks * 32 + g * 8;
    bf16x8 bfr[4];
#pragma unroll
    for (int n = 0; n < 4; ++n)
      if (n < nnt)
        bfr[n] = *(const bf16x8*)(att + ((ntb + n) * 16 + l15) * 200 + c0);
#pragma unroll
    for (int i = 0; i < 3; ++i) {
      const int o = (w_m * 3 + i) * 16 + l15;    // < 192, rows >=180 zero
      const bf16x8 a = *(const bf16x8*)(wo + (size_t)o * EPAD + c0);
#pragma unroll
      for (int n = 0; n < 4; ++n)
        if (n < nnt)
          acc[i][n] = __builtin_amdgcn_mfma_f32_16x16x32_bf16(a, bfr[n], acc[i][n], 0, 0, 0);
    }
  }
#pragma unroll
  for (int i = 0; i < 3; ++i) {
#pragma unroll
    for (int r = 0; r < 4; ++r) {
      const int o = (w_m * 3 + i) * 16 + g * 4 + r;
      if (o < DIM) {
        const float bias = bo[o];
        float* orow = out + ((size_t)b * DIM + o) * LL + t0;
#pragma unroll
        for (int n = 0; n < 4; ++n)
          if (n < nnt) orow[(ntb + n) * 16 + l15] = acc[i][n][r] + bias;
      }
    }
  }
}

// ---- fallback: R5 fused kernel (verbatim, proven) -------------------------
__global__ __launch_bounds__(512, 4) void la_fused(
    const float* __restrict__ fmap, const unsigned short* __restrict__ wqkv,
    const unsigned short* __restrict__ wo_b, const float* __restrict__ bo,
    float* __restrict__ out) {
  __shared__ unsigned short lds[LDS_U16];
  unsigned short* qt  = lds;
  unsigned short* xs  = lds + QT_U16;
  unsigned short* lut = xs + XS_U16;

  const int tid  = (int)threadIdx.x;
  const int wave = tid >> 6;
  const int lane = tid & 63;
  const int l15  = lane & 15;
  const int g    = lane >> 4;

  const int bi    = (int)blockIdx.x;
  const int b     = bi >> 8;
  const int chunk = bi & 255;
  const int t0    = chunk * F_T;

  for (int e = tid; e < EQKV; e += 512) {
    const int part = (e >= 360) ? 2 : ((e >= DIM) ? 1 : 0);
    const int rr = e - part * DIM;
    const int h = rr / 30;
    const int d = rr - h * 30;
    lut[e] = (unsigned short)(part * EPAD + h * 32 + d);
  }

#pragma unroll
  for (int ph = 0; ph < 2; ++ph) {
    const int tb = ph * 32;
    __syncthreads();
#pragma unroll
    for (int it = 0; it < 3; ++it) {
      const int idx = tid + it * 512;
      const int c  = idx >> 3;
      const int tl = (idx & 7) * 4;
      float4 v = {0.f, 0.f, 0.f, 0.f};
      if (c < DIM && (tb + tl) < F_T)
        v = *(const float4*)(fmap + (size_t)(b * DIM + c) * LL + t0 + tb + tl);
      unsigned short* xr = xs + tl * XS_STRIDE + c;
      xr[0 * XS_STRIDE] = f2b(v.x);
      xr[1 * XS_STRIDE] = f2b(v.y);
      xr[2 * XS_STRIDE] = f2b(v.z);
      xr[3 * XS_STRIDE] = f2b(v.w);
    }
    __syncthreads();
    for (int mt = wave; mt < 36; mt += 8) {
      const int e_a = mt * 16 + l15;
      f32x4 acc0 = zero4(), acc1 = zero4();
#pragma unroll
      for (int ks = 0; ks < 6; ++ks) {
        const int c0 = ks * 32 + g * 8;
        const bf16x8 a = (e_a < EQKV)
            ? *(const bf16x8*)(wqkv + (size_t)e_a * EPAD + c0) : zfrag();
        const bf16x8 b0 = *(const bf16x8*)(xs + l15 * XS_STRIDE + c0);
        const bf16x8 b1 = *(const bf16x8*)(xs + (16 + l15) * XS_STRIDE + c0);
        acc0 = __builtin_amdgcn_mfma_f32_16x16x32_bf16(a, b0, acc0, 0, 0, 0);
        acc1 = __builtin_amdgcn_mfma_f32_16x16x32_bf16(a, b1, acc1, 0, 0, 0);
      }
      const int e0 = mt * 16 + g * 4;
#pragma unroll
      for (int nt = 0; nt < 2; ++nt) {
        const f32x4 A = nt ? acc1 : acc0;
        const int t = tb + nt * 16 + l15;
        if (t < F_T) {
          unsigned short* qrow = qt + t * QT_STRIDE;
          if (e0 + 0 < EQKV) qrow[lut[e0 + 0]] = f2b(A[0]);
          if (e0 + 1 < EQKV) qrow[lut[e0 + 1]] = f2b(A[1]);
          if (e0 + 2 < EQKV) qrow[lut[e0 + 2]] = f2b(A[2]);
          if (e0 + 3 < EQKV) qrow[lut[e0 + 3]] = f2b(A[3]);
        }
      }
    }
  }
  __syncthreads();

  if (tid < 336) {
    const float scale = 0.18257418583505536f;
    const int w   = tid / 42;
    const int rem = tid - w * 42;
    const int h   = rem / 7;
    const int i   = rem - h * 7;
    const int ti  = w * 7 + i;
    const uint32_t* qrow = (const uint32_t*)(qt + ti * QT_STRIDE + h * 32);
    const unsigned short* kbase = qt + (w * 7) * QT_STRIDE + EPAD + h * 32;
    float dots[7];
#pragma unroll
    for (int j = 0; j < 7; ++j) dots[j] = 0.f;
#pragma unroll
    for (int dp = 0; dp < 15; ++dp) {
      const uint32_t qu = qrow[dp];
      const float q0 = blo(qu), q1 = bhi(qu);
#pragma unroll
      for (int j = 0; j < 7; ++j) {
        const uint32_t ku = *(const uint32_t*)(kbase + j * QT_STRIDE + dp * 2);
        dots[j] += q0 * blo(ku);
        dots[j] += q1 * bhi(ku);
      }
    }
    float mx = dots[0];
#pragma unroll
    for (int j = 1; j < 7; ++j) mx = fmaxf(mx, dots[j]);
    float aw[7];
    float s = 0.f;
#pragma unroll
    for (int j = 0; j < 7; ++j) {
      const float pj = __expf(scale * (dots[j] - mx));
      aw[j] = pj; s += pj;
    }
    const float inv = 1.f / s;
#pragma unroll
    for (int j = 0; j < 7; ++j) aw[j] *= inv;
    const unsigned short* vbase = qt + (w * 7) * QT_STRIDE + 2 * EPAD + h * 32;
    uint32_t* orow = (uint32_t*)(qt + ti * QT_STRIDE + h * 32);
#pragma unroll
    for (int dp = 0; dp < 15; ++dp) {
      float o0 = 0.f, o1 = 0.f;
#pragma unroll
      for (int j = 0; j < 7; ++j) {
        const uint32_t vu = *(const uint32_t*)(vbase + j * QT_STRIDE + dp * 2);
        o0 += aw[j] * blo(vu);
        o1 += aw[j] * bhi(vu);
      }
      orow[dp] = pack2(o0, o1);
    }
    orow[15] = 0u;
  }
  __syncthreads();

  for (int p = wave; p < 48; p += 8) {
    const int m = p >> 2;
    const int n = p & 3;
    const int o_a  = m * 16 + l15;
    const int tcol = n * 16 + l15;
    const int trd  = (tcol < F_T) ? tcol : (F_T - 1);
    f32x4 acc = zero4();
#pragma unroll
    for (int ks = 0; ks < 6; ++ks) {
      const int c0 = ks * 32 + g * 8;
      const bf16x8 a = (o_a < DIM)
          ? *(const bf16x8*)(wo_b + (size_t)o_a * EPAD + c0) : zfrag();
      const bf16x8 bf = *(const bf16x8*)(qt + trd * QT_STRIDE + c0);
      acc = __builtin_amdgcn_mfma_f32_16x16x32_bf16(a, bf, acc, 0, 0, 0);
    }
    if (tcol < F_T) {
#pragma unroll
      for (int r = 0; r < 4; ++r) {
        const int o = m * 16 + g * 4 + r;
        if (o < DIM)
          out[(size_t)(b * DIM + o) * LL + t0 + tcol] = acc[r] + bo[o];
      }
    }
  }
}

extern "C" void kernel_launch(void* const* d_in, const int* in_sizes, int n_in,
                              void* d_out, int out_size, void* d_ws, size_t ws_size,
                              hipStream_t stream) {
  const float* fmap = (const float*)d_in[0];
  const float* Wq   = (const float*)d_in[1];
  const float* Wkv  = (const float*)d_in[2];
  const float* Wo   = (const float*)d_in[3];
  const float* bo   = (const float*)d_in[4];
  float* o = (float*)d_out;

  unsigned short* wqkv_b = (unsigned short*)d_ws;        // 576*192
  unsigned short* wo_h32 = wqkv_b + 576 * 192;           // 192*192
  unsigned short* wo_nat = wo_h32 + 192 * 192;           // 192*192
  const size_t woff = (size_t)(576 * 192 + 2 * 192 * 192) * 2;  // 368,640 B

  hipLaunchKernelGGL(la_prep, dim3(180), dim3(1024), 0, stream,
                     Wq, Wkv, Wo, wqkv_b, wo_h32, wo_nat);

  const size_t per_batch = (size_t)LL * QROW * 2;        // 15.6 MB
  int SB = 0;
  if      (woff + 16 * per_batch <= ws_size) SB = 16;
  else if (woff +  8 * per_batch <= ws_size) SB = 8;
  else if (woff +  4 * per_batch <= ws_size) SB = 4;
  else if (woff +  2 * per_batch <= ws_size) SB = 2;
  else if (woff +  1 * per_batch <= ws_size) SB = 1;

  if (SB > 0) {
    unsigned short* qkv_ws = (unsigned short*)((char*)d_ws + woff);
    for (int s = 0; s < B; s += SB) {
      hipLaunchKernelGGL(k1_qkv, dim3(SB * 224), dim3(512), 0, stream,
                         fmap, wqkv_b, qkv_ws, s);
      hipLaunchKernelGGL(k2_attn_oproj, dim3(SB * 128), dim3(512), 0, stream,
                         qkv_ws, wo_nat, bo, o, s);
    }
  } else {
    hipLaunchKernelGGL(la_fused, dim3(4096), dim3(512), 0, stream,
                       fmap, wqkv_b, wo_h32, bo, o);
  }
}

// Round 8
// 580.960 us; speedup vs baseline: 2.1564x; 2.1564x over previous
//
#include <hip/hip_runtime.h>
#include <stdint.h>

namespace {

constexpr int DIM  = 180;
constexpr int LL   = 14336;
constexpr int B    = 16;
constexpr int T    = 56;      // tokens per block (8 windows)
constexpr int NCH  = 256;
constexpr int EQKV = 540;

constexpr int QTS = 552;      // qt row stride u16: 1104B (16B-aligned), 276dw = 20 mod 32
constexpr int XSS = 200;      // xs row stride u16: 400B

typedef __attribute__((ext_vector_type(8))) short bf16x8;
typedef __attribute__((ext_vector_type(4))) float f32x4;

union Frag { bf16x8 v; uint32_t u[4]; unsigned short s[8]; };

__device__ __forceinline__ unsigned short f2b(float f) {
  uint32_t u = __builtin_bit_cast(uint32_t, f);
  u = (u + 0x7fffu + ((u >> 16) & 1u)) >> 16;   // RNE
  return (unsigned short)u;
}
__device__ __forceinline__ uint32_t pack2(float lo, float hi) {
  return (uint32_t)f2b(lo) | ((uint32_t)f2b(hi) << 16);
}
__device__ __forceinline__ float blo(uint32_t u) { return __builtin_bit_cast(float, u << 16); }
__device__ __forceinline__ float bhi(uint32_t u) { return __builtin_bit_cast(float, u & 0xffff0000u); }
__device__ __forceinline__ f32x4 zero4() { f32x4 z = {0.f,0.f,0.f,0.f}; return z; }

} // namespace

// ---- prep: weights -> bf16, zero-padded: wqkv_b[576][192], wo_b[192][192] ----
__global__ __launch_bounds__(1024) void la_prep(
    const float* __restrict__ Wq, const float* __restrict__ Wkv,
    const float* __restrict__ Wo, unsigned short* __restrict__ wqkv_b,
    unsigned short* __restrict__ wo_b) {
  const int idx = (int)(blockIdx.x * 1024 + threadIdx.x);
  if (idx < 576 * 192) {
    const int e = idx / 192, c = idx - e * 192;
    float v = 0.f;
    if (e < EQKV && c < DIM)
      v = (e < DIM) ? Wq[e * DIM + c] : Wkv[(size_t)(e - DIM) * DIM + c];
    wqkv_b[idx] = f2b(v);
  } else {
    const int k = idx - 576 * 192;
    if (k < 192 * 192) {
      const int o = k / 192, c = k - o * 192;
      float v = 0.f;
      if (o < DIM && c < DIM) v = Wo[o * DIM + c];
      wo_b[k] = f2b(v);
    }
  }
}

// ---- fused main: 512 threads, T=56 tokens, 2 blocks/CU, LDS 74.6 KB -------
__global__ __launch_bounds__(512, 4) void la_main(
    const float* __restrict__ fmap, const unsigned short* __restrict__ wqkv,
    const unsigned short* __restrict__ wo_b, const float* __restrict__ bo,
    float* __restrict__ out) {
  __shared__ __align__(16) unsigned short qt[T * QTS];   // 61,824 B, natural-e
  __shared__ __align__(16) unsigned short xs[32 * XSS];  // 12,800 B

  const int tid  = (int)threadIdx.x;
  const int wave = tid >> 6;
  const int lane = tid & 63;
  const int l15  = lane & 15;
  const int g    = lane >> 4;

  const int bi    = (int)blockIdx.x;
  const int b     = bi >> 8;
  const int chunk = bi & 255;
  const int t0    = chunk * T;

  // ================= stage 1: qkv = Wqkv @ x -> qt[t][e] (natural e) =======
  const int nt_w  = wave & 1;            // n-tile within the 32-token phase
  const int mg9   = (wave >> 1) * 9;     // 9 m-tiles per wave
  const int tfrag = nt_w * 16 + l15;     // local token col this lane owns (B)

  // ---- phase 0 staging (tokens 0..31)
#pragma unroll
  for (int it = 0; it < 3; ++it) {
    const int idx = tid + it * 512;      // 192 c x 8 token-quads
    const int c  = idx >> 3;
    const int tq = (idx & 7) * 4;
    float4 v = {0.f, 0.f, 0.f, 0.f};
    if (c < DIM)
      v = *(const float4*)(fmap + (size_t)(b * DIM + c) * LL + t0 + tq);
    unsigned short* xr = xs + tq * XSS + c;
    xr[0 * XSS] = f2b(v.x);
    xr[1 * XSS] = f2b(v.y);
    xr[2 * XSS] = f2b(v.z);
    xr[3 * XSS] = f2b(v.w);
  }
  __syncthreads();

  // hoist phase-0 B-fragments to registers (read xs ONCE per wave)
  bf16x8 bf[6];
#pragma unroll
  for (int ks = 0; ks < 6; ++ks)
    bf[ks] = *(const bf16x8*)(xs + tfrag * XSS + ks * 32 + g * 8);

  // prefetch phase-1 x data (latency hides under the phase-0 m-loop)
  float4 stg[3];
#pragma unroll
  for (int it = 0; it < 3; ++it) {
    const int idx = tid + it * 512;
    const int c  = idx >> 3;
    const int tq = 32 + (idx & 7) * 4;
    float4 v = {0.f, 0.f, 0.f, 0.f};
    if (c < DIM && tq < T)
      v = *(const float4*)(fmap + (size_t)(b * DIM + c) * LL + t0 + tq);
    stg[it] = v;
  }

  // phase-0 m-loop: A from L2, B from regs, uint2 writeback
#pragma unroll 3
  for (int k9 = 0; k9 < 9; ++k9) {
    const int mt  = mg9 + k9;
    const int e_a = mt * 16 + l15;       // < 576, zero-padded rows
    f32x4 acc = zero4();
#pragma unroll
    for (int ks = 0; ks < 6; ++ks) {
      const bf16x8 a = *(const bf16x8*)(wqkv + (size_t)e_a * 192 + ks * 32 + g * 8);
      acc = __builtin_amdgcn_mfma_f32_16x16x32_bf16(a, bf[ks], acc, 0, 0, 0);
    }
    const int e0 = mt * 16 + g * 4;
    if (e0 < EQKV) {                     // 540 is 4-aligned: clean cut
      const int t = nt_w * 16 + l15;     // < 32 always valid in ph0
      uint2 pk;
      pk.x = pack2(acc[0], acc[1]);
      pk.y = pack2(acc[2], acc[3]);
      *(uint2*)(qt + t * QTS + e0) = pk;
    }
  }
  __syncthreads();                       // all waves past their B0 hoist

  // ---- phase 1 staging store (tokens 32..55, rows >=56 staged as zeros)
#pragma unroll
  for (int it = 0; it < 3; ++it) {
    const int idx = tid + it * 512;
    const int c  = idx >> 3;
    const int tq = (idx & 7) * 4;        // local row
    unsigned short* xr = xs + tq * XSS + c;
    xr[0 * XSS] = f2b(stg[it].x);
    xr[1 * XSS] = f2b(stg[it].y);
    xr[2 * XSS] = f2b(stg[it].z);
    xr[3 * XSS] = f2b(stg[it].w);
  }
  __syncthreads();

#pragma unroll
  for (int ks = 0; ks < 6; ++ks)
    bf[ks] = *(const bf16x8*)(xs + tfrag * XSS + ks * 32 + g * 8);

#pragma unroll 3
  for (int k9 = 0; k9 < 9; ++k9) {
    const int mt  = mg9 + k9;
    const int e_a = mt * 16 + l15;
    f32x4 acc = zero4();
#pragma unroll
    for (int ks = 0; ks < 6; ++ks) {
      const bf16x8 a = *(const bf16x8*)(wqkv + (size_t)e_a * 192 + ks * 32 + g * 8);
      acc = __builtin_amdgcn_mfma_f32_16x16x32_bf16(a, bf[ks], acc, 0, 0, 0);
    }
    const int e0 = mt * 16 + g * 4;
    const int t  = 32 + nt_w * 16 + l15;
    if (t < T && e0 < EQKV) {
      uint2 pk;
      pk.x = pack2(acc[0], acc[1]);
      pk.y = pack2(acc[2], acc[3]);
      *(uint2*)(qt + t * QTS + e0) = pk;
    }
  }
  __syncthreads();

  // ================= stage 2: windowed softmax-attention ===================
  // natural-e cols: q at 30h, k at 180+30h, v at 360+30h (15h odd-spreads banks)
  if (tid < 336) {  // (w,h,i): 8*6*7
    const float scale = 0.18257418583505536f;  // 30^-0.5
    const int w   = tid / 42;
    const int rem = tid - w * 42;
    const int h   = rem / 7;
    const int i   = rem - h * 7;
    const int ti  = w * 7 + i;
    const int hq  = 30 * h;
    const uint32_t* qrow = (const uint32_t*)(qt + ti * QTS + hq);
    const unsigned short* kbase = qt + (w * 7) * QTS + DIM + hq;
    float dots[7];
#pragma unroll
    for (int j = 0; j < 7; ++j) dots[j] = 0.f;
#pragma unroll
    for (int dp = 0; dp < 15; ++dp) {
      const uint32_t qu = qrow[dp];
      const float q0 = blo(qu), q1 = bhi(qu);
#pragma unroll
      for (int j = 0; j < 7; ++j) {
        const uint32_t ku = *(const uint32_t*)(kbase + j * QTS + dp * 2);
        dots[j] += q0 * blo(ku);
        dots[j] += q1 * bhi(ku);
      }
    }
    float mx = dots[0];
#pragma unroll
    for (int j = 1; j < 7; ++j) mx = fmaxf(mx, dots[j]);
    float aw[7];
    float s = 0.f;
#pragma unroll
    for (int j = 0; j < 7; ++j) {
      const float pj = __expf(scale * (dots[j] - mx));
      aw[j] = pj; s += pj;
    }
    const float inv = 1.f / s;
#pragma unroll
    for (int j = 0; j < 7; ++j) aw[j] *= inv;
    const unsigned short* vbase = qt + (w * 7) * QTS + 2 * DIM + hq;
    uint32_t* orow = (uint32_t*)(qt + ti * QTS + hq);   // overwrite own q slot
#pragma unroll
    for (int dp = 0; dp < 15; ++dp) {
      float o0 = 0.f, o1 = 0.f;
#pragma unroll
      for (int j = 0; j < 7; ++j) {
        const uint32_t vu = *(const uint32_t*)(vbase + j * QTS + dp * 2);
        o0 += aw[j] * blo(vu);
        o1 += aw[j] * bhi(vu);
      }
      orow[dp] = pack2(o0, o1);
    }
    // no zero-pad pass: stage-3 B cols [180,192) hit k junk x zero Wo cols = 0
  }
  __syncthreads();

  // ================= stage 3: y = Wo @ att + bo ============================
  {
    const int n3 = wave & 3;             // n-tile
    const int m3 = (wave >> 2) * 6;      // 6 m-tiles per wave
    const int tc  = n3 * 16 + l15;
    const int trd = (tc < T) ? tc : (T - 1);  // clamped read, store-guarded
    bf16x8 bq[6];
#pragma unroll
    for (int ks = 0; ks < 6; ++ks)
      bq[ks] = *(const bf16x8*)(qt + trd * QTS + ks * 32 + g * 8);
#pragma unroll 3
    for (int k6 = 0; k6 < 6; ++k6) {
      const int m   = m3 + k6;
      const int o_a = m * 16 + l15;      // < 192, zero-padded rows
      f32x4 acc = zero4();
#pragma unroll
      for (int ks = 0; ks < 6; ++ks) {
        const bf16x8 a = *(const bf16x8*)(wo_b + (size_t)o_a * 192 + ks * 32 + g * 8);
        acc = __builtin_amdgcn_mfma_f32_16x16x32_bf16(a, bq[ks], acc, 0, 0, 0);
      }
      if (tc < T) {
#pragma unroll
        for (int r = 0; r < 4; ++r) {
          const int o = m * 16 + g * 4 + r;
          if (o < DIM)
            out[(size_t)(b * DIM + o) * LL + t0 + tc] = acc[r] + bo[o];
        }
      }
    }
  }
}

extern "C" void kernel_launch(void* const* d_in, const int* in_sizes, int n_in,
                              void* d_out, int out_size, void* d_ws, size_t ws_size,
                              hipStream_t stream) {
  const float* fmap = (const float*)d_in[0];
  const float* Wq   = (const float*)d_in[1];
  const float* Wkv  = (const float*)d_in[2];
  const float* Wo   = (const float*)d_in[3];
  const float* bo   = (const float*)d_in[4];
  float* o = (float*)d_out;

  unsigned short* wqkv_b = (unsigned short*)d_ws;        // 576*192 bf16
  unsigned short* wo_b   = wqkv_b + 576 * 192;           // 192*192 bf16

  const int prep_elems = 576 * 192 + 192 * 192;          // 147,456
  hipLaunchKernelGGL(la_prep, dim3((prep_elems + 1023) / 1024), dim3(1024), 0,
                     stream, Wq, Wkv, Wo, wqkv_b, wo_b);
  hipLaunchKernelGGL(la_main, dim3(B * NCH), dim3(512), 0, stream,
                     fmap, wqkv_b, wo_b, bo, o);
}

// Round 9
// 432.263 us; speedup vs baseline: 2.8982x; 1.3440x over previous
//
#include <hip/hip_runtime.h>
#include <stdint.h>

namespace {

constexpr int DIM  = 180;
constexpr int LL   = 14336;
constexpr int B    = 16;
constexpr int T    = 56;      // tokens per block (8 windows)
constexpr int NCH  = 256;
constexpr int EQKV = 540;

constexpr int QTS = 552;      // qt row stride u16: 1104B (16B-aligned), 276dw = 20 mod 32
constexpr int XSS = 200;      // xs row stride u16: 400B

typedef __attribute__((ext_vector_type(8))) short bf16x8;
typedef __attribute__((ext_vector_type(4))) float f32x4;

__device__ __forceinline__ unsigned short f2b(float f) {
  uint32_t u = __builtin_bit_cast(uint32_t, f);
  u = (u + 0x7fffu + ((u >> 16) & 1u)) >> 16;   // RNE
  return (unsigned short)u;
}
__device__ __forceinline__ uint32_t pack2(float lo, float hi) {
  return (uint32_t)f2b(lo) | ((uint32_t)f2b(hi) << 16);
}
__device__ __forceinline__ float blo(uint32_t u) { return __builtin_bit_cast(float, u << 16); }
__device__ __forceinline__ float bhi(uint32_t u) { return __builtin_bit_cast(float, u & 0xffff0000u); }
__device__ __forceinline__ f32x4 zero4() { f32x4 z = {0.f,0.f,0.f,0.f}; return z; }

} // namespace

// ---- prep: weights -> bf16, zero-padded: wqkv_b[576][192], wo_b[192][192] ----
__global__ __launch_bounds__(1024) void la_prep(
    const float* __restrict__ Wq, const float* __restrict__ Wkv,
    const float* __restrict__ Wo, unsigned short* __restrict__ wqkv_b,
    unsigned short* __restrict__ wo_b) {
  const int idx = (int)(blockIdx.x * 1024 + threadIdx.x);
  if (idx < 576 * 192) {
    const int e = idx / 192, c = idx - e * 192;
    float v = 0.f;
    if (e < EQKV && c < DIM)
      v = (e < DIM) ? Wq[e * DIM + c] : Wkv[(size_t)(e - DIM) * DIM + c];
    wqkv_b[idx] = f2b(v);
  } else {
    const int k = idx - 576 * 192;
    if (k < 192 * 192) {
      const int o = k / 192, c = k - o * 192;
      float v = 0.f;
      if (o < DIM && c < DIM) v = Wo[o * DIM + c];
      wo_b[k] = f2b(v);
    }
  }
}

// ---- fused main: 512 threads, T=56, 2 blocks/CU, pipelined A-loads --------
__global__ __launch_bounds__(512, 4) void la_main(
    const float* __restrict__ fmap, const unsigned short* __restrict__ wqkv,
    const unsigned short* __restrict__ wo_b, const float* __restrict__ bo,
    float* __restrict__ out) {
  __shared__ __align__(16) unsigned short qt[T * QTS];   // 61,824 B, natural-e
  __shared__ __align__(16) unsigned short xs[32 * XSS];  // 12,800 B

  const int tid  = (int)threadIdx.x;
  const int wave = tid >> 6;
  const int lane = tid & 63;
  const int l15  = lane & 15;
  const int g    = lane >> 4;

  const int bi    = (int)blockIdx.x;
  const int b     = bi >> 8;
  const int chunk = bi & 255;
  const int t0    = chunk * T;

  const unsigned short* wA = wqkv + (size_t)l15 * 192 + g * 8;  // lane A base

  // ================= stage 1: qkv = Wqkv @ x -> qt[t][e] ===================
#pragma unroll
  for (int ph = 0; ph < 2; ++ph) {
    const int tb = ph * 32;
    // ---- stage 32 tokens into xs (zeros for t >= T)
#pragma unroll
    for (int it = 0; it < 3; ++it) {
      const int idx = tid + it * 512;      // 192 c x 8 token-quads
      const int c  = idx >> 3;
      const int tq = (idx & 7) * 4;
      float4 v = {0.f, 0.f, 0.f, 0.f};
      if (c < DIM && (tb + tq) < T)
        v = *(const float4*)(fmap + (size_t)(b * DIM + c) * LL + t0 + tb + tq);
      unsigned short* xr = xs + tq * XSS + c;
      xr[0 * XSS] = f2b(v.x);
      xr[1 * XSS] = f2b(v.y);
      xr[2 * XSS] = f2b(v.z);
      xr[3 * XSS] = f2b(v.w);
    }
    // preload first m-tile's A-fragments (independent of xs / barrier)
    bf16x8 An[6];
#pragma unroll
    for (int ks = 0; ks < 6; ++ks)
      An[ks] = *(const bf16x8*)(wA + (size_t)(wave * 16) * 192 + ks * 32);
    __syncthreads();
    // hoist this wave's two B-fragment sets (read xs once per phase)
    bf16x8 b0[6], b1[6];
#pragma unroll
    for (int ks = 0; ks < 6; ++ks) {
      b0[ks] = *(const bf16x8*)(xs + l15 * XSS + ks * 32 + g * 8);
      b1[ks] = *(const bf16x8*)(xs + (16 + l15) * XSS + ks * 32 + g * 8);
    }
    // m-loop: 36 m-tiles / 8 waves, A prefetched one m-tile ahead
    int mt = wave;
#pragma unroll 5
    for (int it = 0; it < 5; ++it) {
      if (mt < 36) {
        bf16x8 A[6];
#pragma unroll
        for (int ks = 0; ks < 6; ++ks) A[ks] = An[ks];
        const int mtn = mt + 8;
        if (mtn < 36) {
#pragma unroll
          for (int ks = 0; ks < 6; ++ks)
            An[ks] = *(const bf16x8*)(wA + (size_t)(mtn * 16) * 192 + ks * 32);
        }
        f32x4 a0 = zero4(), a1 = zero4();
#pragma unroll
        for (int ks = 0; ks < 6; ++ks) {
          a0 = __builtin_amdgcn_mfma_f32_16x16x32_bf16(A[ks], b0[ks], a0, 0, 0, 0);
          a1 = __builtin_amdgcn_mfma_f32_16x16x32_bf16(A[ks], b1[ks], a1, 0, 0, 0);
        }
        const int e0 = mt * 16 + g * 4;
        if (e0 < EQKV) {                   // 540 is 4-aligned: clean cut
          const int ta = tb + l15;         // always < T
          uint2 pk;
          pk.x = pack2(a0[0], a0[1]);
          pk.y = pack2(a0[2], a0[3]);
          *(uint2*)(qt + ta * QTS + e0) = pk;
          const int tb2 = tb + 16 + l15;
          if (tb2 < T) {
            uint2 pk2;
            pk2.x = pack2(a1[0], a1[1]);
            pk2.y = pack2(a1[2], a1[3]);
            *(uint2*)(qt + tb2 * QTS + e0) = pk2;
          }
        }
      }
      mt += 8;
    }
    __syncthreads();
  }

  // ================= stage 2: windowed softmax-attention ===================
  // 672 tasks = (w,h,i) x d-half over 512 threads, 2 guarded rounds.
  // Halves interleave dp = half + 2*dq (lanes stay convergent); partner lanes
  // (2k, 2k+1) combine dots via shfl_xor. Each (w,h,i)'s q-slice is read and
  // written only by its own lane pair; k/v are read-only -> no barrier inside.
  const float scale = 0.18257418583505536f;  // 30^-0.5
#pragma unroll
  for (int rnd = 0; rnd < 2; ++rnd) {
    const int task = tid + rnd * 512;
    if (task < 672) {
      const int pair = task >> 1;
      const int half = task & 1;
      const int w    = pair / 42;
      const int rem  = pair - w * 42;
      const int h    = rem / 7;
      const int i    = rem - h * 7;
      const int ti   = w * 7 + i;
      const int hq   = 30 * h;
      const unsigned short* qp = qt + ti * QTS + hq;
      const unsigned short* kb = qt + (w * 7) * QTS + DIM + hq;
      const unsigned short* vb = qt + (w * 7) * QTS + 2 * DIM + hq;
      float dots[7];
#pragma unroll
      for (int j = 0; j < 7; ++j) dots[j] = 0.f;
#pragma unroll
      for (int dq = 0; dq < 8; ++dq) {
        const int dp = half + 2 * dq;
        if (dp < 15) {
          const uint32_t qu = *(const uint32_t*)(qp + 2 * dp);
          const float q0 = blo(qu), q1 = bhi(qu);
#pragma unroll
          for (int j = 0; j < 7; ++j) {
            const uint32_t ku = *(const uint32_t*)(kb + j * QTS + 2 * dp);
            dots[j] += q0 * blo(ku);
            dots[j] += q1 * bhi(ku);
          }
        }
      }
#pragma unroll
      for (int j = 0; j < 7; ++j) dots[j] += __shfl_xor(dots[j], 1);
      float mx = dots[0];
#pragma unroll
      for (int j = 1; j < 7; ++j) mx = fmaxf(mx, dots[j]);
      float aw[7];
      float s = 0.f;
#pragma unroll
      for (int j = 0; j < 7; ++j) {
        const float pj = __expf(scale * (dots[j] - mx));
        aw[j] = pj; s += pj;
      }
      const float inv = 1.f / s;
#pragma unroll
      for (int j = 0; j < 7; ++j) aw[j] *= inv;
      uint32_t* orow = (uint32_t*)(qt + ti * QTS + hq);  // own q slot
#pragma unroll
      for (int dq = 0; dq < 8; ++dq) {
        const int dp = half + 2 * dq;
        if (dp < 15) {
          float o0 = 0.f, o1 = 0.f;
#pragma unroll
          for (int j = 0; j < 7; ++j) {
            const uint32_t vu = *(const uint32_t*)(vb + j * QTS + 2 * dp);
            o0 += aw[j] * blo(vu);
            o1 += aw[j] * bhi(vu);
          }
          orow[dp] = pack2(o0, o1);
        }
      }
      // stage-3 B cols [180,192) read k-residue x zero Wo cols = 0
    }
  }
  __syncthreads();

  // ================= stage 3: y = Wo @ att + bo (pipelined A) ==============
  {
    const int n3 = wave & 3;
    const int m3 = (wave >> 2) * 6;      // 6 m-tiles per wave
    const int tc  = n3 * 16 + l15;
    const int trd = (tc < T) ? tc : (T - 1);  // clamped read, store-guarded
    bf16x8 bq[6];
#pragma unroll
    for (int ks = 0; ks < 6; ++ks)
      bq[ks] = *(const bf16x8*)(qt + trd * QTS + ks * 32 + g * 8);
    const unsigned short* wO = wo_b + (size_t)l15 * 192 + g * 8;
    bf16x8 An[6];
#pragma unroll
    for (int ks = 0; ks < 6; ++ks)
      An[ks] = *(const bf16x8*)(wO + (size_t)(m3 * 16) * 192 + ks * 32);
#pragma unroll 6
    for (int k6 = 0; k6 < 6; ++k6) {
      const int m = m3 + k6;
      bf16x8 A[6];
#pragma unroll
      for (int ks = 0; ks < 6; ++ks) A[ks] = An[ks];
      if (k6 < 5) {
#pragma unroll
        for (int ks = 0; ks < 6; ++ks)
          An[ks] = *(const bf16x8*)(wO + (size_t)((m + 1) * 16) * 192 + ks * 32);
      }
      f32x4 acc = zero4();
#pragma unroll
      for (int ks = 0; ks < 6; ++ks)
        acc = __builtin_amdgcn_mfma_f32_16x16x32_bf16(A[ks], bq[ks], acc, 0, 0, 0);
      if (tc < T) {
#pragma unroll
        for (int r = 0; r < 4; ++r) {
          const int o = m * 16 + g * 4 + r;
          if (o < DIM)
            out[(size_t)(b * DIM + o) * LL + t0 + tc] = acc[r] + bo[o];
        }
      }
    }
  }
}

extern "C" void kernel_launch(void* const* d_in, const int* in_sizes, int n_in,
                              void* d_out, int out_size, void* d_ws, size_t ws_size,
                              hipStream_t stream) {
  const float* fmap = (const float*)d_in[0];
  const float* Wq   = (const float*)d_in[1];
  const float* Wkv  = (const float*)d_in[2];
  const float* Wo   = (const float*)d_in[3];
  const float* bo   = (const float*)d_in[4];
  float* o = (float*)d_out;

  unsigned short* wqkv_b = (unsigned short*)d_ws;        // 576*192 bf16
  unsigned short* wo_b   = wqkv_b + 576 * 192;           // 192*192 bf16

  const int prep_elems = 576 * 192 + 192 * 192;          // 147,456
  hipLaunchKernelGGL(la_prep, dim3((prep_elems + 1023) / 1024), dim3(1024), 0,
                     stream, Wq, Wkv, Wo, wqkv_b, wo_b);
  hipLaunchKernelGGL(la_main, dim3(B * NCH), dim3(512), 0, stream,
                     fmap, wqkv_b, wo_b, bo, o);
}